// Round 3
// baseline (564.228 us; speedup 1.0000x reference)
//
#include <hip/hip_runtime.h>
#include <hip/hip_bf16.h>

#define DIM 2048
#define NH 16
#define NKV 4
#define HD 128
#define B_ 2
#define T_ 2048
#define M_TOT (B_*T_)
#define NQKV 3072   // fused projection width: 2048 q + 512 k + 512 v

typedef __attribute__((ext_vector_type(8))) short short8;
typedef __attribute__((ext_vector_type(4))) float f32x4;

typedef const __attribute__((address_space(1))) void* gptr_t;
typedef __attribute__((address_space(3))) void* lptr_t;

__device__ __forceinline__ ushort f2bf(float f) {
  unsigned u = __builtin_bit_cast(unsigned, f);
  u += 0x7fffu + ((u >> 16) & 1u);
  return (ushort)(u >> 16);
}

// ---------- cast f32 -> bf16, 8 elems/thread ----------
__global__ void cast_bf16_kernel(const float* __restrict__ in, ushort* __restrict__ out, int n8) {
  int i = blockIdx.x * blockDim.x + threadIdx.x;
  if (i >= n8) return;
  const float4* p = (const float4*)in + (size_t)i*2;
  float4 a = p[0], b = p[1];
  short8 o;
  o[0]=f2bf(a.x); o[1]=f2bf(a.y); o[2]=f2bf(a.z); o[3]=f2bf(a.w);
  o[4]=f2bf(b.x); o[5]=f2bf(b.y); o[6]=f2bf(b.z); o[7]=f2bf(b.w);
  *((short8*)out + i) = o;
}

// ---------- transpose + cast: in f32 [K][N] -> out bf16 [N][K] ----------
__global__ void transpose_cast(const float* __restrict__ in, ushort* __restrict__ out, int K, int N) {
  __shared__ float tile[32][33];
  int n0 = blockIdx.x*32, k0 = blockIdx.y*32;
  int tx = threadIdx.x, ty = threadIdx.y;
  #pragma unroll
  for (int i=0;i<32;i+=8) tile[ty+i][tx] = in[(size_t)(k0+ty+i)*N + n0+tx];
  __syncthreads();
  #pragma unroll
  for (int i=0;i<32;i+=8) out[(size_t)(n0+ty+i)*K + k0+tx] = f2bf(tile[tx][ty+i]);
}

// ---------- GEMM: C[M][N] = A[M][K] * Bt[N][K]^T  (bf16 in, f32 out), m97 structure ----------
__global__ __launch_bounds__(256) void gemm_bt(const ushort* __restrict__ A, const ushort* __restrict__ Bt,
                                               float* __restrict__ C, int M, int N, int K) {
  __shared__ ushort Ash[128*64];
  __shared__ ushort Bsh[128*64];
  int tid = threadIdx.x;
  int lane = tid & 63, wave = tid >> 6;
  int lo = lane & 15, hi = lane >> 4;
  int m0 = blockIdx.y * 128, n0 = blockIdx.x * 128;
  int wr = wave >> 1, wc = wave & 1;
  f32x4 acc[4][4] = {};
  int srow = tid >> 3;
  int scol = (tid & 7) * 8;
  const ushort* Abase = A + (size_t)(m0 + srow)*K + scol;
  const ushort* Bbase = Bt + (size_t)(n0 + srow)*K + scol;
  for (int k0 = 0; k0 < K; k0 += 64) {
    #pragma unroll
    for (int c = 0; c < 4; ++c)
      __builtin_amdgcn_global_load_lds((gptr_t)(Abase + (size_t)c*32*K + k0),
                                       (lptr_t)&Ash[(srow + c*32)*64 + scol], 16, 0, 0);
    #pragma unroll
    for (int c = 0; c < 4; ++c)
      __builtin_amdgcn_global_load_lds((gptr_t)(Bbase + (size_t)c*32*K + k0),
                                       (lptr_t)&Bsh[(srow + c*32)*64 + scol], 16, 0, 0);
    __syncthreads();
    #pragma unroll
    for (int kk = 0; kk < 2; ++kk) {
      short8 a[4], b[4];
      #pragma unroll
      for (int m=0;m<4;m++) a[m] = *(const short8*)&Ash[(wr*64 + m*16 + lo)*64 + kk*32 + hi*8];
      #pragma unroll
      for (int n=0;n<4;n++) b[n] = *(const short8*)&Bsh[(wc*64 + n*16 + lo)*64 + kk*32 + hi*8];
      #pragma unroll
      for (int m=0;m<4;m++)
        #pragma unroll
        for (int n=0;n<4;n++)
          acc[m][n] = __builtin_amdgcn_mfma_f32_16x16x32_bf16(a[m], b[n], acc[m][n], 0, 0, 0);
    }
    __syncthreads();
  }
  #pragma unroll
  for (int m=0;m<4;m++)
    #pragma unroll
    for (int n=0;n<4;n++) {
      int row = m0 + wr*64 + m*16 + hi*4;
      int col = n0 + wc*64 + n*16 + lo;
      #pragma unroll
      for (int r=0;r<4;r++)
        C[(size_t)(row + r)*N + col] = acc[m][n][r];
    }
}

// ---------- RoPE + cache writes (reads fused qkv_f [M][3072]) ----------
__global__ __launch_bounds__(256) void rope_prep(const float* __restrict__ qkv,
                         const float* __restrict__ freqs,
                         ushort* __restrict__ q_bf, ushort* __restrict__ k_bf,
                         float* __restrict__ kcache, float* __restrict__ vcache) {
  __shared__ float fc[128];
  int row = blockIdx.x;                 // b*T + t
  int b = row >> 11, t = row & 2047;
  int tid = threadIdx.x;
  if (tid < 128) fc[tid] = freqs[(size_t)t*128 + tid];
  __syncthreads();
  const float QSCALE = 0.08838834764831845f * 1.4426950408889634f; // 1/sqrt(HD) * log2(e)
  const float2* rowp = (const float2*)qkv + (size_t)row*(NQKV/2);
  #pragma unroll
  for (int i = 0; i < 4; ++i) {
    int p = tid + i*256;                // q pair 0..1023
    int h = p >> 6, j = p & 63;
    float c = fc[2*j], s = fc[2*j+1];
    float2 x = rowp[h*64 + j];
    float o0 = (x.x*c - x.y*s) * QSCALE;
    float o1 = (x.x*s + x.y*c) * QSCALE;
    size_t idx = ((size_t)(b*NH + h)*T_ + t)*HD + 2*j;
    ((unsigned*)q_bf)[idx/2] = (unsigned)f2bf(o0) | ((unsigned)f2bf(o1) << 16);
  }
  {
    int p = tid;                        // k pair 0..255
    int g = p >> 6, j = p & 63;
    float c = fc[2*j], s = fc[2*j+1];
    float2 x = rowp[1024 + g*64 + j];
    float o0 = x.x*c - x.y*s;
    float o1 = x.x*s + x.y*c;
    size_t idx = ((size_t)(b*NKV + g)*T_ + t)*HD + 2*j;
    ((unsigned*)k_bf)[idx/2] = (unsigned)f2bf(o0) | ((unsigned)f2bf(o1) << 16);
    ((float2*)kcache)[idx/2] = make_float2(o0, o1);
  }
  {
    int f = tid;                        // v float2 0..255 (NKV*HD/2 = 256 per row)
    int g = f >> 6, d2 = f & 63;
    float2 v = rowp[1280 + g*64 + d2];
    ((float2*)vcache)[((size_t)(b*NKV + g)*T_ + t)*64 + d2] = v;
  }
}

// ---------- V transpose: qkv_f v-part -> vt bf16 [B,NKV,HD,T] ----------
__global__ void v_transpose(const float* __restrict__ qkv, ushort* __restrict__ vt) {
  __shared__ float tile[32][33];
  int bg = blockIdx.z; int b = bg >> 2, g = bg & 3;
  int t0 = blockIdx.x*32, d0 = blockIdx.y*32;
  int tx = threadIdx.x, ty = threadIdx.y;
  #pragma unroll
  for (int i=0;i<32;i+=8)
    tile[ty+i][tx] = qkv[(size_t)(b*T_ + t0+ty+i)*NQKV + 2560 + g*HD + d0 + tx];
  __syncthreads();
  #pragma unroll
  for (int i=0;i<32;i+=8)
    vt[((size_t)bg*HD + d0+ty+i)*T_ + t0 + tx] = f2bf(tile[tx][ty+i]);
}

// ---------- flash attention: 64 q-rows/block, KVBLK=64 ----------
__global__ __launch_bounds__(256) void attn_kernel(const ushort* __restrict__ Qb, const ushort* __restrict__ Kb,
                          const ushort* __restrict__ Vt, ushort* __restrict__ O) {
  __shared__ ushort Ksh[64][136];
  __shared__ ushort Vsh[128][72];
  __shared__ ushort Psh[4][16][72];
  int qt = blockIdx.x, h = blockIdx.y, b = blockIdx.z, g = h >> 2;
  int tid = threadIdx.x, wave = tid >> 6, lane = tid & 63;
  int lo = lane & 15, hi = lane >> 4;
  int q0 = qt*64 + wave*16;
  const ushort* Qrow = Qb + ((size_t)(b*NH + h)*T_ + q0 + lo)*HD;
  short8 qfr[4];
  #pragma unroll
  for (int kf=0;kf<4;kf++) qfr[kf] = *(const short8*)(Qrow + kf*32 + hi*8);
  f32x4 o[8] = {};
  float mrow[4] = {-1e30f,-1e30f,-1e30f,-1e30f};
  float lrow[4] = {0.f,0.f,0.f,0.f};
  const ushort* Kbase = Kb + (size_t)(b*NKV + g)*T_*HD;
  const ushort* Vbase = Vt + (size_t)(b*NKV + g)*HD*T_;
  int ntiles = qt + 1;
  for (int it = 0; it < ntiles; ++it) {
    int kv0 = it*64;
    {
      int r = tid >> 4, cl = (tid & 15)*8;
      #pragma unroll
      for (int c=0;c<4;c++)
        *(short8*)&Ksh[r + c*16][cl] = *(const short8*)(Kbase + (size_t)(kv0 + r + c*16)*HD + cl);
    }
    {
      int r = tid >> 3, cl = (tid & 7)*8;
      #pragma unroll
      for (int c=0;c<4;c++)
        *(short8*)&Vsh[r + c*32][cl] = *(const short8*)(Vbase + (size_t)(r + c*32)*T_ + kv0 + cl);
    }
    __syncthreads();
    f32x4 s[4];
    #pragma unroll
    for (int nf=0;nf<4;nf++) {
      s[nf] = (f32x4){0.f,0.f,0.f,0.f};
      #pragma unroll
      for (int kf=0;kf<4;kf++) {
        short8 bk = *(const short8*)&Ksh[nf*16 + lo][kf*32 + hi*8];
        s[nf] = __builtin_amdgcn_mfma_f32_16x16x32_bf16(qfr[kf], bk, s[nf], 0,0,0);
      }
    }
    if (it == ntiles-1) {
      #pragma unroll
      for (int nf=0;nf<4;nf++)
        #pragma unroll
        for (int r=0;r<4;r++) {
          int kvg = kv0 + nf*16 + lo;
          int qg = q0 + hi*4 + r;
          if (kvg > qg) s[nf][r] = -1e30f;
        }
    }
    float pscale[4];
    #pragma unroll
    for (int r=0;r<4;r++) {
      float mx = fmaxf(fmaxf(s[0][r], s[1][r]), fmaxf(s[2][r], s[3][r]));
      mx = fmaxf(mx, __shfl_xor(mx, 1));
      mx = fmaxf(mx, __shfl_xor(mx, 2));
      mx = fmaxf(mx, __shfl_xor(mx, 4));
      mx = fmaxf(mx, __shfl_xor(mx, 8));
      float nm = fmaxf(mrow[r], mx);
      float scl = exp2f(mrow[r] - nm);
      mrow[r] = nm;
      float rs = 0.f;
      #pragma unroll
      for (int nf=0;nf<4;nf++) { float pv = exp2f(s[nf][r] - nm); s[nf][r] = pv; rs += pv; }
      rs += __shfl_xor(rs, 1); rs += __shfl_xor(rs, 2);
      rs += __shfl_xor(rs, 4); rs += __shfl_xor(rs, 8);
      lrow[r] = lrow[r]*scl + rs;
      pscale[r] = scl;
    }
    #pragma unroll
    for (int df=0;df<8;df++)
      #pragma unroll
      for (int r=0;r<4;r++) o[df][r] *= pscale[r];
    #pragma unroll
    for (int nf=0;nf<4;nf++)
      #pragma unroll
      for (int r=0;r<4;r++)
        Psh[wave][hi*4 + r][nf*16 + lo] = f2bf(s[nf][r]);
    asm volatile("s_waitcnt lgkmcnt(0)" ::: "memory");
    short8 pa[2];
    #pragma unroll
    for (int k2=0;k2<2;k2++) pa[k2] = *(const short8*)&Psh[wave][lo][k2*32 + hi*8];
    #pragma unroll
    for (int df=0;df<8;df++) {
      #pragma unroll
      for (int k2=0;k2<2;k2++) {
        short8 bv = *(const short8*)&Vsh[df*16 + lo][k2*32 + hi*8];
        o[df] = __builtin_amdgcn_mfma_f32_16x16x32_bf16(pa[k2], bv, o[df], 0,0,0);
      }
    }
    __syncthreads();
  }
  #pragma unroll
  for (int r=0;r<4;r++) {
    float inv = 1.0f / lrow[r];
    int qg = q0 + hi*4 + r;
    size_t base = ((size_t)(b*T_) + qg)*DIM + (size_t)h*HD;
    #pragma unroll
    for (int df=0;df<8;df++)
      O[base + df*16 + lo] = f2bf(o[df][r] * inv);
  }
}

extern "C" void kernel_launch(void* const* d_in, const int* in_sizes, int n_in,
                              void* d_out, int out_size, void* d_ws, size_t ws_size,
                              hipStream_t stream) {
  const float* x     = (const float*)d_in[0];
  const float* wq    = (const float*)d_in[1];
  const float* wk    = (const float*)d_in[2];
  const float* wv    = (const float*)d_in[3];
  const float* wo    = (const float*)d_in[4];
  const float* freqs = (const float*)d_in[5];
  float* out    = (float*)d_out;
  float* kcache = out + (size_t)B_*T_*DIM;
  float* vcache = kcache + (size_t)B_*NKV*T_*HD;

  char* ws = (char*)d_ws;
  size_t off = 0;
  auto alloc = [&](size_t bytes) { char* p = ws + off; off += (bytes + 255) & ~255ULL; return p; };
  ushort* x_bf   = (ushort*)alloc((size_t)M_TOT*DIM*2);
  ushort* wqkv_t = (ushort*)alloc((size_t)NQKV*DIM*2);  // rows: 2048 q, 512 k, 512 v (each [n][K])
  ushort* wo_t   = (ushort*)alloc((size_t)DIM*DIM*2);
  float*  qkv_f  = (float*)alloc((size_t)M_TOT*NQKV*4);
  ushort* q_bf   = (ushort*)alloc((size_t)B_*NH*T_*HD*2);
  ushort* k_bf   = (ushort*)alloc((size_t)B_*NKV*T_*HD*2);
  ushort* v_t    = (ushort*)alloc((size_t)B_*NKV*HD*T_*2);
  ushort* ao_bf  = (ushort*)alloc((size_t)M_TOT*DIM*2);
  (void)ws_size; (void)in_sizes; (void)n_in; (void)out_size;

  cast_bf16_kernel<<<(M_TOT*DIM/8 + 255)/256, 256, 0, stream>>>(x, x_bf, M_TOT*DIM/8);
  dim3 tb(32, 8);
  transpose_cast<<<dim3(DIM/32, DIM/32), tb, 0, stream>>>(wq, wqkv_t, DIM, DIM);
  transpose_cast<<<dim3(512/32, DIM/32), tb, 0, stream>>>(wk, wqkv_t + (size_t)2048*DIM, DIM, 512);
  transpose_cast<<<dim3(512/32, DIM/32), tb, 0, stream>>>(wv, wqkv_t + (size_t)2560*DIM, DIM, 512);
  transpose_cast<<<dim3(DIM/32, DIM/32), tb, 0, stream>>>(wo, wo_t, DIM, DIM);

  gemm_bt<<<dim3(NQKV/128, M_TOT/128), 256, 0, stream>>>(x_bf, wqkv_t, qkv_f, M_TOT, NQKV, DIM);

  rope_prep<<<M_TOT, 256, 0, stream>>>(qkv_f, freqs, q_bf, k_bf, kcache, vcache);
  v_transpose<<<dim3(T_/32, HD/32, B_*NKV), tb, 0, stream>>>(qkv_f, v_t);

  attn_kernel<<<dim3(T_/64, NH, B_), 256, 0, stream>>>(q_bf, k_bf, v_t, ao_bf);

  gemm_bt<<<dim3(DIM/128, M_TOT/128), 256, 0, stream>>>(ao_bf, wo_t, out, M_TOT, DIM, DIM);
}

// Round 4
// 454.918 us; speedup vs baseline: 1.2403x; 1.2403x over previous
//
#include <hip/hip_runtime.h>
#include <hip/hip_bf16.h>

#define DIM 2048
#define NH 16
#define NKV 4
#define HD 128
#define B_ 2
#define T_ 2048
#define M_TOT (B_*T_)
#define NQKV 3072   // fused projection width: 2048 q + 512 k + 512 v

typedef __attribute__((ext_vector_type(8))) short short8;
typedef __attribute__((ext_vector_type(4))) float f32x4;

typedef const __attribute__((address_space(1))) void* gptr_t;
typedef __attribute__((address_space(3))) void* lptr_t;

__device__ __forceinline__ ushort f2bf(float f) {
  unsigned u = __builtin_bit_cast(unsigned, f);
  u += 0x7fffu + ((u >> 16) & 1u);
  return (ushort)(u >> 16);
}

// ---------- cast f32 -> bf16, 8 elems/thread ----------
__global__ void cast_bf16_kernel(const float* __restrict__ in, ushort* __restrict__ out, int n8) {
  int i = blockIdx.x * blockDim.x + threadIdx.x;
  if (i >= n8) return;
  const float4* p = (const float4*)in + (size_t)i*2;
  float4 a = p[0], b = p[1];
  short8 o;
  o[0]=f2bf(a.x); o[1]=f2bf(a.y); o[2]=f2bf(a.z); o[3]=f2bf(a.w);
  o[4]=f2bf(b.x); o[5]=f2bf(b.y); o[6]=f2bf(b.z); o[7]=f2bf(b.w);
  *((short8*)out + i) = o;
}

// ---------- transpose + cast: in f32 [K][N] -> out bf16 [N][K] ----------
__global__ void transpose_cast(const float* __restrict__ in, ushort* __restrict__ out, int K, int N) {
  __shared__ float tile[32][33];
  int n0 = blockIdx.x*32, k0 = blockIdx.y*32;
  int tx = threadIdx.x, ty = threadIdx.y;
  #pragma unroll
  for (int i=0;i<32;i+=8) tile[ty+i][tx] = in[(size_t)(k0+ty+i)*N + n0+tx];
  __syncthreads();
  #pragma unroll
  for (int i=0;i<32;i+=8) out[(size_t)(n0+ty+i)*K + k0+tx] = f2bf(tile[tx][ty+i]);
}

// ---------- GEMM: C[M][N] = A[M][K] * Bt[N][K]^T  (bf16 in, f32 out), m97 structure ----------
__global__ __launch_bounds__(256) void gemm_bt(const ushort* __restrict__ A, const ushort* __restrict__ Bt,
                                               float* __restrict__ C, int M, int N, int K) {
  __shared__ ushort Ash[128*64];
  __shared__ ushort Bsh[128*64];
  int tid = threadIdx.x;
  int lane = tid & 63, wave = tid >> 6;
  int lo = lane & 15, hi = lane >> 4;
  int m0 = blockIdx.y * 128, n0 = blockIdx.x * 128;
  int wr = wave >> 1, wc = wave & 1;
  f32x4 acc[4][4] = {};
  int srow = tid >> 3;
  int scol = (tid & 7) * 8;
  const ushort* Abase = A + (size_t)(m0 + srow)*K + scol;
  const ushort* Bbase = Bt + (size_t)(n0 + srow)*K + scol;
  for (int k0 = 0; k0 < K; k0 += 64) {
    #pragma unroll
    for (int c = 0; c < 4; ++c)
      __builtin_amdgcn_global_load_lds((gptr_t)(Abase + (size_t)c*32*K + k0),
                                       (lptr_t)&Ash[(srow + c*32)*64 + scol], 16, 0, 0);
    #pragma unroll
    for (int c = 0; c < 4; ++c)
      __builtin_amdgcn_global_load_lds((gptr_t)(Bbase + (size_t)c*32*K + k0),
                                       (lptr_t)&Bsh[(srow + c*32)*64 + scol], 16, 0, 0);
    __syncthreads();
    #pragma unroll
    for (int kk = 0; kk < 2; ++kk) {
      short8 a[4], b[4];
      #pragma unroll
      for (int m=0;m<4;m++) a[m] = *(const short8*)&Ash[(wr*64 + m*16 + lo)*64 + kk*32 + hi*8];
      #pragma unroll
      for (int n=0;n<4;n++) b[n] = *(const short8*)&Bsh[(wc*64 + n*16 + lo)*64 + kk*32 + hi*8];
      #pragma unroll
      for (int m=0;m<4;m++)
        #pragma unroll
        for (int n=0;n<4;n++)
          acc[m][n] = __builtin_amdgcn_mfma_f32_16x16x32_bf16(a[m], b[n], acc[m][n], 0, 0, 0);
    }
    __syncthreads();
  }
  #pragma unroll
  for (int m=0;m<4;m++)
    #pragma unroll
    for (int n=0;n<4;n++) {
      int row = m0 + wr*64 + m*16 + hi*4;
      int col = n0 + wc*64 + n*16 + lo;
      #pragma unroll
      for (int r=0;r<4;r++)
        C[(size_t)(row + r)*N + col] = acc[m][n][r];
    }
}

// ---------- RoPE + cache writes (reads fused qkv_f [M][3072]) ----------
__global__ __launch_bounds__(256) void rope_prep(const float* __restrict__ qkv,
                         const float* __restrict__ freqs,
                         ushort* __restrict__ q_bf, ushort* __restrict__ k_bf,
                         float* __restrict__ kcache, float* __restrict__ vcache) {
  __shared__ float fc[128];
  int row = blockIdx.x;                 // b*T + t
  int b = row >> 11, t = row & 2047;
  int tid = threadIdx.x;
  if (tid < 128) fc[tid] = freqs[(size_t)t*128 + tid];
  __syncthreads();
  const float QSCALE = 0.08838834764831845f * 1.4426950408889634f; // 1/sqrt(HD) * log2(e)
  const float2* rowp = (const float2*)qkv + (size_t)row*(NQKV/2);
  #pragma unroll
  for (int i = 0; i < 4; ++i) {
    int p = tid + i*256;                // q pair 0..1023
    int h = p >> 6, j = p & 63;
    float c = fc[2*j], s = fc[2*j+1];
    float2 x = rowp[h*64 + j];
    float o0 = (x.x*c - x.y*s) * QSCALE;
    float o1 = (x.x*s + x.y*c) * QSCALE;
    size_t idx = ((size_t)(b*NH + h)*T_ + t)*HD + 2*j;
    ((unsigned*)q_bf)[idx/2] = (unsigned)f2bf(o0) | ((unsigned)f2bf(o1) << 16);
  }
  {
    int p = tid;                        // k pair 0..255
    int g = p >> 6, j = p & 63;
    float c = fc[2*j], s = fc[2*j+1];
    float2 x = rowp[1024 + g*64 + j];
    float o0 = x.x*c - x.y*s;
    float o1 = x.x*s + x.y*c;
    size_t idx = ((size_t)(b*NKV + g)*T_ + t)*HD + 2*j;
    ((unsigned*)k_bf)[idx/2] = (unsigned)f2bf(o0) | ((unsigned)f2bf(o1) << 16);
    ((float2*)kcache)[idx/2] = make_float2(o0, o1);
  }
  {
    int f = tid;                        // v float2 0..255 (NKV*HD/2 = 256 per row)
    int g = f >> 6, d2 = f & 63;
    float2 v = rowp[1280 + g*64 + d2];
    ((float2*)vcache)[((size_t)(b*NKV + g)*T_ + t)*64 + d2] = v;
  }
}

// ---------- V transpose: qkv_f v-part -> vt bf16 [B,NKV,HD,T] ----------
__global__ void v_transpose(const float* __restrict__ qkv, ushort* __restrict__ vt) {
  __shared__ float tile[32][33];
  int bg = blockIdx.z; int b = bg >> 2, g = bg & 3;
  int t0 = blockIdx.x*32, d0 = blockIdx.y*32;
  int tx = threadIdx.x, ty = threadIdx.y;
  #pragma unroll
  for (int i=0;i<32;i+=8)
    tile[ty+i][tx] = qkv[(size_t)(b*T_ + t0+ty+i)*NQKV + 2560 + g*HD + d0 + tx];
  __syncthreads();
  #pragma unroll
  for (int i=0;i<32;i+=8)
    vt[((size_t)bg*HD + d0+ty+i)*T_ + t0 + tx] = f2bf(tile[tx][ty+i]);
}

// ---------- flash attention: 64 q-rows/block, KVBLK=64, swapped QK^T ----------
// grid: 1024 blocks; qt remapped so each CU's block set {id, id+256, id+512, id+768}
// has qts {u, 15-u, 16+u, 31-u} -> constant 66 tile-iters per CU.
__global__ __launch_bounds__(256) void attn_kernel(const ushort* __restrict__ Qb, const ushort* __restrict__ Kb,
                          const ushort* __restrict__ Vt, ushort* __restrict__ O) {
  __shared__ ushort Ksh[64][144];      // 288B row: 4-way max bank pattern on b128 reads
  __shared__ unsigned Pshu[4][16][40]; // per-wave P, dword-packed, 160B row
  int id = blockIdx.x;
  int j = id >> 5, hb = id & 31;
  int t2 = j >> 3, u = j & 7;
  int qt = (t2==0) ? u : (t2==1) ? 15-u : (t2==2) ? 16+u : 31-u;
  int h = hb & 15, b = hb >> 4, g = h >> 2;
  int tid = threadIdx.x, wave = tid >> 6, lane = tid & 63;
  int lo = lane & 15, hi = lane >> 4;
  int q0 = qt*64 + wave*16;
  const ushort* Qrow = Qb + ((size_t)(b*NH + h)*T_ + q0 + lo)*HD;
  short8 qfr[4];
  #pragma unroll
  for (int kf=0;kf<4;kf++) qfr[kf] = *(const short8*)(Qrow + kf*32 + hi*8);
  f32x4 o[8] = {};
  float m_run = -1e30f, l_run = 0.f;   // this lane's q-row = q0 + lo
  const ushort* Kbase = Kb + (size_t)(b*NKV + g)*T_*HD;
  const ushort* Vbase = Vt + (size_t)(b*NKV + g)*HD*T_;
  int ntiles = qt + 1;
  for (int it = 0; it < ntiles; ++it) {
    int kv0 = it*64;
    {
      int r = tid >> 4, cl = (tid & 15)*8;
      #pragma unroll
      for (int c=0;c<4;c++)
        *(short8*)&Ksh[r + c*16][cl] = *(const short8*)(Kbase + (size_t)(kv0 + r + c*16)*HD + cl);
    }
    __syncthreads();
    // S^T = K * Q^T : s[nf][r] = S[q0+lo][kv0 + nf*16 + hi*4 + r]
    f32x4 s[4];
    __builtin_amdgcn_s_setprio(1);
    #pragma unroll
    for (int nf=0;nf<4;nf++) {
      s[nf] = (f32x4){0.f,0.f,0.f,0.f};
      #pragma unroll
      for (int kf=0;kf<4;kf++) {
        short8 bk = *(const short8*)&Ksh[nf*16 + lo][kf*32 + hi*8];
        s[nf] = __builtin_amdgcn_mfma_f32_16x16x32_bf16(bk, qfr[kf], s[nf], 0,0,0);
      }
    }
    __builtin_amdgcn_s_setprio(0);
    if (it == ntiles-1) {
      int qg = q0 + lo;
      #pragma unroll
      for (int nf=0;nf<4;nf++)
        #pragma unroll
        for (int r=0;r<4;r++) {
          int kvg = kv0 + nf*16 + hi*4 + r;
          if (kvg > qg) s[nf][r] = -1e30f;
        }
    }
    // in-lane softmax over this lane's 16 S-values; reduce across hi groups (2 levels)
    float mx = -1e30f;
    #pragma unroll
    for (int nf=0;nf<4;nf++)
      #pragma unroll
      for (int r=0;r<4;r++) mx = fmaxf(mx, s[nf][r]);
    mx = fmaxf(mx, __shfl_xor(mx, 16));
    mx = fmaxf(mx, __shfl_xor(mx, 32));
    float nm = fmaxf(m_run, mx);
    float scl = exp2f(m_run - nm);
    m_run = nm;
    float rs = 0.f;
    #pragma unroll
    for (int nf=0;nf<4;nf++)
      #pragma unroll
      for (int r=0;r<4;r++) { float pv = exp2f(s[nf][r] - nm); s[nf][r] = pv; rs += pv; }
    rs += __shfl_xor(rs, 16);
    rs += __shfl_xor(rs, 32);
    l_run = l_run*scl + rs;
    // broadcast rescale factors for the o-fragment rows (q = q0 + hi*4 + r)
    float ps[4];
    #pragma unroll
    for (int r=0;r<4;r++) ps[r] = __shfl(scl, (lane & 48) + hi*4 + r);
    #pragma unroll
    for (int df=0;df<8;df++)
      #pragma unroll
      for (int r=0;r<4;r++) o[df][r] *= ps[r];
    // P -> LDS (dword-packed): row q=lo, cols kv = nf*16 + hi*4 + {0..3}
    #pragma unroll
    for (int nf=0;nf<4;nf++) {
      Pshu[wave][lo][nf*8 + hi*2]     = (unsigned)f2bf(s[nf][0]) | ((unsigned)f2bf(s[nf][1]) << 16);
      Pshu[wave][lo][nf*8 + hi*2 + 1] = (unsigned)f2bf(s[nf][2]) | ((unsigned)f2bf(s[nf][3]) << 16);
    }
    asm volatile("s_waitcnt lgkmcnt(0)" ::: "memory");
    short8 pa[2];
    #pragma unroll
    for (int k2=0;k2<2;k2++)
      pa[k2] = *(const short8*)&((const ushort*)&Pshu[wave][lo][0])[k2*32 + hi*8];
    __builtin_amdgcn_s_setprio(1);
    #pragma unroll
    for (int df=0;df<8;df++) {
      #pragma unroll
      for (int k2=0;k2<2;k2++) {
        short8 bv = *(const short8*)(Vbase + (size_t)(df*16 + lo)*T_ + kv0 + k2*32 + hi*8);
        o[df] = __builtin_amdgcn_mfma_f32_16x16x32_bf16(pa[k2], bv, o[df], 0,0,0);
      }
    }
    __builtin_amdgcn_s_setprio(0);
    __syncthreads();
  }
  #pragma unroll
  for (int r=0;r<4;r++) {
    float li = __shfl(l_run, (lane & 48) + hi*4 + r);
    float inv = 1.0f / li;
    int qg = q0 + hi*4 + r;
    size_t base = ((size_t)(b*T_) + qg)*DIM + (size_t)h*HD;
    #pragma unroll
    for (int df=0;df<8;df++)
      O[base + df*16 + lo] = f2bf(o[df][r] * inv);
  }
}

extern "C" void kernel_launch(void* const* d_in, const int* in_sizes, int n_in,
                              void* d_out, int out_size, void* d_ws, size_t ws_size,
                              hipStream_t stream) {
  const float* x     = (const float*)d_in[0];
  const float* wq    = (const float*)d_in[1];
  const float* wk    = (const float*)d_in[2];
  const float* wv    = (const float*)d_in[3];
  const float* wo    = (const float*)d_in[4];
  const float* freqs = (const float*)d_in[5];
  float* out    = (float*)d_out;
  float* kcache = out + (size_t)B_*T_*DIM;
  float* vcache = kcache + (size_t)B_*NKV*T_*HD;

  char* ws = (char*)d_ws;
  size_t off = 0;
  auto alloc = [&](size_t bytes) { char* p = ws + off; off += (bytes + 255) & ~255ULL; return p; };
  ushort* x_bf   = (ushort*)alloc((size_t)M_TOT*DIM*2);
  ushort* wqkv_t = (ushort*)alloc((size_t)NQKV*DIM*2);  // rows: 2048 q, 512 k, 512 v (each [n][K])
  ushort* wo_t   = (ushort*)alloc((size_t)DIM*DIM*2);
  float*  qkv_f  = (float*)alloc((size_t)M_TOT*NQKV*4);
  ushort* q_bf   = (ushort*)alloc((size_t)B_*NH*T_*HD*2);
  ushort* k_bf   = (ushort*)alloc((size_t)B_*NKV*T_*HD*2);
  ushort* v_t    = (ushort*)alloc((size_t)B_*NKV*HD*T_*2);
  ushort* ao_bf  = (ushort*)alloc((size_t)M_TOT*DIM*2);
  (void)ws_size; (void)in_sizes; (void)n_in; (void)out_size;

  cast_bf16_kernel<<<(M_TOT*DIM/8 + 255)/256, 256, 0, stream>>>(x, x_bf, M_TOT*DIM/8);
  dim3 tb(32, 8);
  transpose_cast<<<dim3(DIM/32, DIM/32), tb, 0, stream>>>(wq, wqkv_t, DIM, DIM);
  transpose_cast<<<dim3(512/32, DIM/32), tb, 0, stream>>>(wk, wqkv_t + (size_t)2048*DIM, DIM, 512);
  transpose_cast<<<dim3(512/32, DIM/32), tb, 0, stream>>>(wv, wqkv_t + (size_t)2560*DIM, DIM, 512);
  transpose_cast<<<dim3(DIM/32, DIM/32), tb, 0, stream>>>(wo, wo_t, DIM, DIM);

  gemm_bt<<<dim3(NQKV/128, M_TOT/128), 256, 0, stream>>>(x_bf, wqkv_t, qkv_f, M_TOT, NQKV, DIM);

  rope_prep<<<M_TOT, 256, 0, stream>>>(qkv_f, freqs, q_bf, k_bf, kcache, vcache);
  v_transpose<<<dim3(T_/32, HD/32, B_*NKV), tb, 0, stream>>>(qkv_f, v_t);

  attn_kernel<<<1024, 256, 0, stream>>>(q_bf, k_bf, v_t, ao_bf);

  gemm_bt<<<dim3(DIM/128, M_TOT/128), 256, 0, stream>>>(ao_bf, wo_t, out, M_TOT, DIM, DIM);
}

// Round 7
// 431.047 us; speedup vs baseline: 1.3090x; 1.0554x over previous
//
#include <hip/hip_runtime.h>
#include <hip/hip_bf16.h>

#define DIM 2048
#define NH 16
#define NKV 4
#define HD 128
#define B_ 2
#define T_ 2048
#define M_TOT (B_*T_)
#define NQKV 3072   // fused projection width: 2048 q + 512 k + 512 v

typedef __attribute__((ext_vector_type(8))) short short8;
typedef __attribute__((ext_vector_type(4))) short short4_t;
typedef __attribute__((ext_vector_type(4))) float f32x4;

typedef const __attribute__((address_space(1))) void* gptr_t;
typedef __attribute__((address_space(3))) void* lptr_t;

__device__ __forceinline__ ushort f2bf(float f) {
  unsigned u = __builtin_bit_cast(unsigned, f);
  u += 0x7fffu + ((u >> 16) & 1u);
  return (ushort)(u >> 16);
}

// ---------- fused prep: x cast (blocks 0..4095), wq/wk/wv/wo transpose+cast ----------
// wq tiles 4096..8191, wk 8192..9215, wv 9216..10239, wo 10240..14335.
__global__ __launch_bounds__(256) void prep_kernel(
    const float* __restrict__ x, const float* __restrict__ wq,
    const float* __restrict__ wk, const float* __restrict__ wv,
    const float* __restrict__ wo,
    ushort* __restrict__ x_bf, ushort* __restrict__ wqkv_t, ushort* __restrict__ wo_t) {
  __shared__ float tile[32][33];
  int id = blockIdx.x, tid = threadIdx.x;
  if (id < 4096) {                       // x cast: 8 f32 -> 8 bf16 per thread
    int i = id*256 + tid;                // covers M_TOT*DIM/8 = 1048576 exactly
    const float4* p = (const float4*)x + (size_t)i*2;
    float4 a = p[0], b = p[1];
    short8 o;
    o[0]=f2bf(a.x); o[1]=f2bf(a.y); o[2]=f2bf(a.z); o[3]=f2bf(a.w);
    o[4]=f2bf(b.x); o[5]=f2bf(b.y); o[6]=f2bf(b.z); o[7]=f2bf(b.w);
    *((short8*)x_bf + i) = o;
    return;
  }
  const float* in; ushort* out; int lg, tt;  // in f32 [2048][N] -> out bf16 [N][2048]
  if (id < 8192)       { in = wq; out = wqkv_t;                    lg = 6; tt = id - 4096; }
  else if (id < 9216)  { in = wk; out = wqkv_t + (size_t)2048*DIM; lg = 4; tt = id - 8192; }
  else if (id < 10240) { in = wv; out = wqkv_t + (size_t)2560*DIM; lg = 4; tt = id - 9216; }
  else                 { in = wo; out = wo_t;                      lg = 6; tt = id - 10240; }
  int N = 32 << lg;
  int n0 = (tt & ((1 << lg) - 1))*32, k0 = (tt >> lg)*32;
  int tx = tid & 31, ty = tid >> 5;
  #pragma unroll
  for (int i=0;i<32;i+=8) tile[ty+i][tx] = in[(size_t)(k0+ty+i)*N + n0+tx];
  __syncthreads();
  #pragma unroll
  for (int i=0;i<32;i+=8) out[(size_t)(n0+ty+i)*DIM + k0+tx] = f2bf(tile[tx][ty+i]);
}

// ---------- GEMM: C[M][N] = A[M][K] * Bt[N][K]^T  (bf16 in, f32 out), m97 structure ----------
__global__ __launch_bounds__(256) void gemm_bt(const ushort* __restrict__ A, const ushort* __restrict__ Bt,
                                               float* __restrict__ C, int M, int N, int K) {
  __shared__ ushort Ash[128*64];
  __shared__ ushort Bsh[128*64];
  int tid = threadIdx.x;
  int lane = tid & 63, wave = tid >> 6;
  int lo = lane & 15, hi = lane >> 4;
  int m0 = blockIdx.y * 128, n0 = blockIdx.x * 128;
  int wr = wave >> 1, wc = wave & 1;
  f32x4 acc[4][4] = {};
  int srow = tid >> 3;
  int scol = (tid & 7) * 8;
  const ushort* Abase = A + (size_t)(m0 + srow)*K + scol;
  const ushort* Bbase = Bt + (size_t)(n0 + srow)*K + scol;
  for (int k0 = 0; k0 < K; k0 += 64) {
    #pragma unroll
    for (int c = 0; c < 4; ++c)
      __builtin_amdgcn_global_load_lds((gptr_t)(Abase + (size_t)c*32*K + k0),
                                       (lptr_t)&Ash[(srow + c*32)*64 + scol], 16, 0, 0);
    #pragma unroll
    for (int c = 0; c < 4; ++c)
      __builtin_amdgcn_global_load_lds((gptr_t)(Bbase + (size_t)c*32*K + k0),
                                       (lptr_t)&Bsh[(srow + c*32)*64 + scol], 16, 0, 0);
    __syncthreads();
    #pragma unroll
    for (int kk = 0; kk < 2; ++kk) {
      short8 a[4], b[4];
      #pragma unroll
      for (int m=0;m<4;m++) a[m] = *(const short8*)&Ash[(wr*64 + m*16 + lo)*64 + kk*32 + hi*8];
      #pragma unroll
      for (int n=0;n<4;n++) b[n] = *(const short8*)&Bsh[(wc*64 + n*16 + lo)*64 + kk*32 + hi*8];
      #pragma unroll
      for (int m=0;m<4;m++)
        #pragma unroll
        for (int n=0;n<4;n++)
          acc[m][n] = __builtin_amdgcn_mfma_f32_16x16x32_bf16(a[m], b[n], acc[m][n], 0, 0, 0);
    }
    __syncthreads();
  }
  #pragma unroll
  for (int m=0;m<4;m++)
    #pragma unroll
    for (int n=0;n<4;n++) {
      int row = m0 + wr*64 + m*16 + hi*4;
      int col = n0 + wc*64 + n*16 + lo;
      #pragma unroll
      for (int r=0;r<4;r++)
        C[(size_t)(row + r)*N + col] = acc[m][n][r];
    }
}

// ---------- QKV GEMM with fused RoPE + cache/layout epilogue ----------
// A[M_TOT][DIM] bf16, Bt[NQKV][DIM] bf16 (rows: 2048 q, 512 k, 512 v).
// Writes: q_bf [B,NH,T,HD] bf16 (roped, pre-scaled), k_bf [B,NKV,T,HD] bf16 (roped),
//         kcache f32 (roped), vcache f32, v_t [B*NKV,HD,T] bf16 (transposed).
__global__ __launch_bounds__(256) void gemm_qkv_rope(
    const ushort* __restrict__ A, const ushort* __restrict__ Bt,
    const float* __restrict__ freqs,
    ushort* __restrict__ q_bf, ushort* __restrict__ k_bf,
    float* __restrict__ kcache, float* __restrict__ vcache,
    ushort* __restrict__ v_t) {
  const int K = DIM;
  __shared__ ushort Ash[128*64];
  __shared__ ushort Bsh[128*64];
  int tid = threadIdx.x;
  int lane = tid & 63, wave = tid >> 6;
  int lo = lane & 15, hi = lane >> 4;
  int m0 = blockIdx.y * 128, n0 = blockIdx.x * 128;
  int wr = wave >> 1, wc = wave & 1;
  f32x4 acc[4][4] = {};
  int srow = tid >> 3;
  int scol = (tid & 7) * 8;
  const ushort* Abase = A + (size_t)(m0 + srow)*K + scol;
  const ushort* Bbase = Bt + (size_t)(n0 + srow)*K + scol;
  for (int k0 = 0; k0 < K; k0 += 64) {
    #pragma unroll
    for (int c = 0; c < 4; ++c)
      __builtin_amdgcn_global_load_lds((gptr_t)(Abase + (size_t)c*32*K + k0),
                                       (lptr_t)&Ash[(srow + c*32)*64 + scol], 16, 0, 0);
    #pragma unroll
    for (int c = 0; c < 4; ++c)
      __builtin_amdgcn_global_load_lds((gptr_t)(Bbase + (size_t)c*32*K + k0),
                                       (lptr_t)&Bsh[(srow + c*32)*64 + scol], 16, 0, 0);
    __syncthreads();
    #pragma unroll
    for (int kk = 0; kk < 2; ++kk) {
      short8 a[4], b[4];
      #pragma unroll
      for (int m=0;m<4;m++) a[m] = *(const short8*)&Ash[(wr*64 + m*16 + lo)*64 + kk*32 + hi*8];
      #pragma unroll
      for (int n=0;n<4;n++) b[n] = *(const short8*)&Bsh[(wc*64 + n*16 + lo)*64 + kk*32 + hi*8];
      #pragma unroll
      for (int m=0;m<4;m++)
        #pragma unroll
        for (int n=0;n<4;n++)
          acc[m][n] = __builtin_amdgcn_mfma_f32_16x16x32_bf16(a[m], b[n], acc[m][n], 0, 0, 0);
    }
    __syncthreads();
  }
  const float QSCALE = 0.08838834764831845f * 1.4426950408889634f; // 1/sqrt(HD)*log2(e)
  #pragma unroll
  for (int m=0;m<4;m++) {
    int row0 = m0 + wr*64 + m*16 + hi*4;          // global token, multiple of 4
    int bb = row0 >> 11, t0 = row0 & 2047;
    #pragma unroll
    for (int n=0;n<4;n++) {
      int col = n0 + wc*64 + n*16 + lo;           // feature 0..3071; parity(col)==parity(lo)
      f32x4 a = acc[m][n];
      if (col < 2048) {                           // Q: rope + scale -> q_bf
        int hh = col >> 7, d = col & 127, jj = d >> 1;
        bool ev = (d & 1) == 0;
        #pragma unroll
        for (int r=0;r<4;r++) {
          float p = __shfl_xor(a[r], 1);
          float2 cs = ((const float2*)freqs)[(size_t)(t0 + r)*64 + jj];
          float o = ev ? (a[r]*cs.x - p*cs.y) : (a[r]*cs.x + p*cs.y);
          q_bf[((size_t)(bb*NH + hh)*T_ + t0 + r)*HD + d] = f2bf(o * QSCALE);
        }
      } else if (col < 2560) {                    // K: rope -> k_bf + kcache
        int cg = col - 2048;
        int gg = cg >> 7, d = cg & 127, jj = d >> 1;
        bool ev = (d & 1) == 0;
        #pragma unroll
        for (int r=0;r<4;r++) {
          float p = __shfl_xor(a[r], 1);
          float2 cs = ((const float2*)freqs)[(size_t)(t0 + r)*64 + jj];
          float o = ev ? (a[r]*cs.x - p*cs.y) : (a[r]*cs.x + p*cs.y);
          size_t idx = ((size_t)(bb*NKV + gg)*T_ + t0 + r)*HD + d;
          k_bf[idx] = f2bf(o);
          kcache[idx] = o;
        }
      } else {                                    // V: vcache f32 + v_t transposed bf16
        int cg = col - 2560;
        int gg = cg >> 7, d = cg & 127;
        short4_t pk;
        #pragma unroll
        for (int r=0;r<4;r++) {
          vcache[((size_t)(bb*NKV + gg)*T_ + t0 + r)*HD + d] = a[r];
          pk[r] = (short)f2bf(a[r]);
        }
        *(short4_t*)&v_t[((size_t)(bb*NKV + gg)*HD + d)*T_ + t0] = pk;
      }
    }
  }
}

// ---------- flash attention: 64 q-rows/block, KVBLK=128, swapped QK^T ----------
// grid: 1024 blocks; qt remapped so each CU's block set {id, id+256, id+512, id+768}
// has qts {u, 15-u, 16+u, 31-u} -> constant 34 kv128-tile-iters per CU.
__global__ __launch_bounds__(256) void attn_kernel(const ushort* __restrict__ Qb, const ushort* __restrict__ Kb,
                          const ushort* __restrict__ Vt, ushort* __restrict__ O) {
  __shared__ ushort Ksh[128][144];     // 288B row: 4-way max bank pattern on b128 reads
  __shared__ unsigned Pshu[4][16][40]; // per-wave P half (16q x 64kv), dword-packed
  int id = blockIdx.x;
  int j = id >> 5, hb = id & 31;
  int t2 = j >> 3, u = j & 7;
  int qt = (t2==0) ? u : (t2==1) ? 15-u : (t2==2) ? 16+u : 31-u;
  int h = hb & 15, b = hb >> 4, g = h >> 2;
  int tid = threadIdx.x, wave = tid >> 6, lane = tid & 63;
  int lo = lane & 15, hi = lane >> 4;
  int q0 = qt*64 + wave*16;
  const ushort* Qrow = Qb + ((size_t)(b*NH + h)*T_ + q0 + lo)*HD;
  short8 qfr[4];
  #pragma unroll
  for (int kf=0;kf<4;kf++) qfr[kf] = *(const short8*)(Qrow + kf*32 + hi*8);
  f32x4 o[8] = {};
  float m_run = -1e30f, l_run = 0.f;   // this lane's q-row = q0 + lo
  const ushort* Kbase = Kb + (size_t)(b*NKV + g)*T_*HD;
  const ushort* Vbase = Vt + (size_t)(b*NKV + g)*HD*T_;
  int ntiles = (qt >> 1) + 1;
  for (int it = 0; it < ntiles; ++it) {
    int kv0 = it*128;
    {
      int r = tid >> 4, cl = (tid & 15)*8;
      #pragma unroll
      for (int c=0;c<8;c++)
        *(short8*)&Ksh[r + c*16][cl] = *(const short8*)(Kbase + (size_t)(kv0 + r + c*16)*HD + cl);
    }
    __syncthreads();
    // S^T = K * Q^T : s[nf][r] = S[q0+lo][kv0 + nf*16 + hi*4 + r]
    f32x4 s[8];
    __builtin_amdgcn_s_setprio(1);
    #pragma unroll
    for (int nf=0;nf<8;nf++) {
      s[nf] = (f32x4){0.f,0.f,0.f,0.f};
      #pragma unroll
      for (int kf=0;kf<4;kf++) {
        short8 bk = *(const short8*)&Ksh[nf*16 + lo][kf*32 + hi*8];
        s[nf] = __builtin_amdgcn_mfma_f32_16x16x32_bf16(bk, qfr[kf], s[nf], 0,0,0);
      }
    }
    __builtin_amdgcn_s_setprio(0);
    if (it == ntiles-1) {
      int qg = q0 + lo;
      #pragma unroll
      for (int nf=0;nf<8;nf++)
        #pragma unroll
        for (int r=0;r<4;r++) {
          int kvg = kv0 + nf*16 + hi*4 + r;
          if (kvg > qg) s[nf][r] = -1e30f;
        }
    }
    // in-lane softmax over this lane's 32 S-values; reduce across hi groups (2 levels)
    float mx = -1e30f;
    #pragma unroll
    for (int nf=0;nf<8;nf++)
      #pragma unroll
      for (int r=0;r<4;r++) mx = fmaxf(mx, s[nf][r]);
    mx = fmaxf(mx, __shfl_xor(mx, 16));
    mx = fmaxf(mx, __shfl_xor(mx, 32));
    float nm = fmaxf(m_run, mx);
    float scl = exp2f(m_run - nm);
    m_run = nm;
    float rs = 0.f;
    #pragma unroll
    for (int nf=0;nf<8;nf++)
      #pragma unroll
      for (int r=0;r<4;r++) { float pv = exp2f(s[nf][r] - nm); s[nf][r] = pv; rs += pv; }
    rs += __shfl_xor(rs, 16);
    rs += __shfl_xor(rs, 32);
    l_run = l_run*scl + rs;
    // broadcast rescale factors for the o-fragment rows (q = q0 + hi*4 + r)
    float ps[4];
    #pragma unroll
    for (int r=0;r<4;r++) ps[r] = __shfl(scl, (lane & 48) + hi*4 + r);
    #pragma unroll
    for (int df=0;df<8;df++)
      #pragma unroll
      for (int r=0;r<4;r++) o[df][r] *= ps[r];
    // PV in two 64-kv halves, P through per-wave LDS
    #pragma unroll
    for (int h2=0; h2<2; ++h2) {
      #pragma unroll
      for (int nf4=0;nf4<4;nf4++) {
        f32x4 sv = s[h2*4 + nf4];
        Pshu[wave][lo][nf4*8 + hi*2]     = (unsigned)f2bf(sv[0]) | ((unsigned)f2bf(sv[1]) << 16);
        Pshu[wave][lo][nf4*8 + hi*2 + 1] = (unsigned)f2bf(sv[2]) | ((unsigned)f2bf(sv[3]) << 16);
      }
      asm volatile("s_waitcnt lgkmcnt(0)" ::: "memory");
      short8 pa[2];
      #pragma unroll
      for (int k2=0;k2<2;k2++)
        pa[k2] = *(const short8*)&((const ushort*)&Pshu[wave][lo][0])[k2*32 + hi*8];
      __builtin_amdgcn_s_setprio(1);
      #pragma unroll
      for (int df=0;df<8;df++) {
        #pragma unroll
        for (int k2=0;k2<2;k2++) {
          short8 bv = *(const short8*)(Vbase + (size_t)(df*16 + lo)*T_ + kv0 + h2*64 + k2*32 + hi*8);
          o[df] = __builtin_amdgcn_mfma_f32_16x16x32_bf16(pa[k2], bv, o[df], 0,0,0);
        }
      }
      __builtin_amdgcn_s_setprio(0);
    }
    __syncthreads();
  }
  #pragma unroll
  for (int r=0;r<4;r++) {
    float li = __shfl(l_run, (lane & 48) + hi*4 + r);
    float inv = 1.0f / li;
    int qg = q0 + hi*4 + r;
    size_t base = ((size_t)(b*T_) + qg)*DIM + (size_t)h*HD;
    #pragma unroll
    for (int df=0;df<8;df++)
      O[base + df*16 + lo] = f2bf(o[df][r] * inv);
  }
}

extern "C" void kernel_launch(void* const* d_in, const int* in_sizes, int n_in,
                              void* d_out, int out_size, void* d_ws, size_t ws_size,
                              hipStream_t stream) {
  const float* x     = (const float*)d_in[0];
  const float* wq    = (const float*)d_in[1];
  const float* wk    = (const float*)d_in[2];
  const float* wv    = (const float*)d_in[3];
  const float* wo    = (const float*)d_in[4];
  const float* freqs = (const float*)d_in[5];
  float* out    = (float*)d_out;
  float* kcache = out + (size_t)B_*T_*DIM;
  float* vcache = kcache + (size_t)B_*NKV*T_*HD;

  char* ws = (char*)d_ws;
  size_t off = 0;
  auto alloc = [&](size_t bytes) { char* p = ws + off; off += (bytes + 255) & ~255ULL; return p; };
  ushort* x_bf   = (ushort*)alloc((size_t)M_TOT*DIM*2);
  ushort* wqkv_t = (ushort*)alloc((size_t)NQKV*DIM*2);  // rows: 2048 q, 512 k, 512 v (each [n][K])
  ushort* wo_t   = (ushort*)alloc((size_t)DIM*DIM*2);
  ushort* q_bf   = (ushort*)alloc((size_t)B_*NH*T_*HD*2);
  ushort* k_bf   = (ushort*)alloc((size_t)B_*NKV*T_*HD*2);
  ushort* v_t    = (ushort*)alloc((size_t)B_*NKV*HD*T_*2);
  ushort* ao_bf  = (ushort*)alloc((size_t)M_TOT*DIM*2);
  (void)ws_size; (void)in_sizes; (void)n_in; (void)out_size;

  prep_kernel<<<14336, 256, 0, stream>>>(x, wq, wk, wv, wo, x_bf, wqkv_t, wo_t);

  gemm_qkv_rope<<<dim3(NQKV/128, M_TOT/128), 256, 0, stream>>>(
      x_bf, wqkv_t, freqs, q_bf, k_bf, kcache, vcache, v_t);

  attn_kernel<<<1024, 256, 0, stream>>>(q_bf, k_bf, v_t, ao_bf);

  gemm_bt<<<dim3(DIM/128, M_TOT/128), 256, 0, stream>>>(ao_bf, wo_t, out, M_TOT, DIM, DIM);
}

// Round 10
// 417.844 us; speedup vs baseline: 1.3503x; 1.0316x over previous
//
#include <hip/hip_runtime.h>
#include <hip/hip_bf16.h>

#define DIM 2048
#define NH 16
#define NKV 4
#define HD 128
#define B_ 2
#define T_ 2048
#define M_TOT (B_*T_)
#define NQKV 3072   // fused projection width: 2048 q + 512 k + 512 v

typedef __attribute__((ext_vector_type(8))) short short8;
typedef __attribute__((ext_vector_type(4))) short short4_t;
typedef __attribute__((ext_vector_type(4))) float f32x4;

typedef const __attribute__((address_space(1))) void* gptr_t;
typedef __attribute__((address_space(3))) void* lptr_t;

__device__ __forceinline__ ushort f2bf(float f) {
  unsigned u = __builtin_bit_cast(unsigned, f);
  u += 0x7fffu + ((u >> 16) & 1u);
  return (ushort)(u >> 16);
}

__device__ __forceinline__ float fast_exp2(float x) {
  float r;
  asm("v_exp_f32 %0, %1" : "=v"(r) : "v"(x));
  return r;
}

__device__ __forceinline__ unsigned cvt_pk_bf16(float a, float b) {
  unsigned r;
  asm("v_cvt_pk_bf16_f32 %0, %1, %2" : "=v"(r) : "v"(a), "v"(b));
  return r;
}

// ---------- fused prep: x cast (blocks 0..4095), wq/wk/wv/wo transpose+cast ----------
__global__ __launch_bounds__(256) void prep_kernel(
    const float* __restrict__ x, const float* __restrict__ wq,
    const float* __restrict__ wk, const float* __restrict__ wv,
    const float* __restrict__ wo,
    ushort* __restrict__ x_bf, ushort* __restrict__ wqkv_t, ushort* __restrict__ wo_t) {
  __shared__ float tile[32][33];
  int id = blockIdx.x, tid = threadIdx.x;
  if (id < 4096) {                       // x cast: 8 f32 -> 8 bf16 per thread
    int i = id*256 + tid;                // covers M_TOT*DIM/8 = 1048576 exactly
    const float4* p = (const float4*)x + (size_t)i*2;
    float4 a = p[0], b = p[1];
    short8 o;
    o[0]=f2bf(a.x); o[1]=f2bf(a.y); o[2]=f2bf(a.z); o[3]=f2bf(a.w);
    o[4]=f2bf(b.x); o[5]=f2bf(b.y); o[6]=f2bf(b.z); o[7]=f2bf(b.w);
    *((short8*)x_bf + i) = o;
    return;
  }
  const float* in; ushort* out; int lg, tt;  // in f32 [2048][N] -> out bf16 [N][2048]
  if (id < 8192)       { in = wq; out = wqkv_t;                    lg = 6; tt = id - 4096; }
  else if (id < 9216)  { in = wk; out = wqkv_t + (size_t)2048*DIM; lg = 4; tt = id - 8192; }
  else if (id < 10240) { in = wv; out = wqkv_t + (size_t)2560*DIM; lg = 4; tt = id - 9216; }
  else                 { in = wo; out = wo_t;                      lg = 6; tt = id - 10240; }
  int N = 32 << lg;
  int n0 = (tt & ((1 << lg) - 1))*32, k0 = (tt >> lg)*32;
  int tx = tid & 31, ty = tid >> 5;
  #pragma unroll
  for (int i=0;i<32;i+=8) tile[ty+i][tx] = in[(size_t)(k0+ty+i)*N + n0+tx];
  __syncthreads();
  #pragma unroll
  for (int i=0;i<32;i+=8) out[(size_t)(n0+ty+i)*DIM + k0+tx] = f2bf(tile[tx][ty+i]);
}

// ---------- GEMM: C[M][N] = A[M][K] * Bt[N][K]^T  (bf16 in, f32 out), m97 structure ----------
__global__ __launch_bounds__(256) void gemm_bt(const ushort* __restrict__ A, const ushort* __restrict__ Bt,
                                               float* __restrict__ C, int M, int N, int K) {
  __shared__ ushort Ash[128*64];
  __shared__ ushort Bsh[128*64];
  int tid = threadIdx.x;
  int lane = tid & 63, wave = tid >> 6;
  int lo = lane & 15, hi = lane >> 4;
  int m0 = blockIdx.y * 128, n0 = blockIdx.x * 128;
  int wr = wave >> 1, wc = wave & 1;
  f32x4 acc[4][4] = {};
  int srow = tid >> 3;
  int scol = (tid & 7) * 8;
  const ushort* Abase = A + (size_t)(m0 + srow)*K + scol;
  const ushort* Bbase = Bt + (size_t)(n0 + srow)*K + scol;
  for (int k0 = 0; k0 < K; k0 += 64) {
    #pragma unroll
    for (int c = 0; c < 4; ++c)
      __builtin_amdgcn_global_load_lds((gptr_t)(Abase + (size_t)c*32*K + k0),
                                       (lptr_t)&Ash[(srow + c*32)*64 + scol], 16, 0, 0);
    #pragma unroll
    for (int c = 0; c < 4; ++c)
      __builtin_amdgcn_global_load_lds((gptr_t)(Bbase + (size_t)c*32*K + k0),
                                       (lptr_t)&Bsh[(srow + c*32)*64 + scol], 16, 0, 0);
    __syncthreads();
    #pragma unroll
    for (int kk = 0; kk < 2; ++kk) {
      short8 a[4], b[4];
      #pragma unroll
      for (int m=0;m<4;m++) a[m] = *(const short8*)&Ash[(wr*64 + m*16 + lo)*64 + kk*32 + hi*8];
      #pragma unroll
      for (int n=0;n<4;n++) b[n] = *(const short8*)&Bsh[(wc*64 + n*16 + lo)*64 + kk*32 + hi*8];
      #pragma unroll
      for (int m=0;m<4;m++)
        #pragma unroll
        for (int n=0;n<4;n++)
          acc[m][n] = __builtin_amdgcn_mfma_f32_16x16x32_bf16(a[m], b[n], acc[m][n], 0, 0, 0);
    }
    __syncthreads();
  }
  #pragma unroll
  for (int m=0;m<4;m++)
    #pragma unroll
    for (int n=0;n<4;n++) {
      int row = m0 + wr*64 + m*16 + hi*4;
      int col = n0 + wc*64 + n*16 + lo;
      #pragma unroll
      for (int r=0;r<4;r++)
        C[(size_t)(row + r)*N + col] = acc[m][n][r];
    }
}

// ---------- QKV GEMM with fused RoPE + cache/layout epilogue ----------
__global__ __launch_bounds__(256) void gemm_qkv_rope(
    const ushort* __restrict__ A, const ushort* __restrict__ Bt,
    const float* __restrict__ freqs,
    ushort* __restrict__ q_bf, ushort* __restrict__ k_bf,
    float* __restrict__ kcache, float* __restrict__ vcache,
    ushort* __restrict__ v_t) {
  const int K = DIM;
  __shared__ ushort Ash[128*64];
  __shared__ ushort Bsh[128*64];
  int tid = threadIdx.x;
  int lane = tid & 63, wave = tid >> 6;
  int lo = lane & 15, hi = lane >> 4;
  int m0 = blockIdx.y * 128, n0 = blockIdx.x * 128;
  int wr = wave >> 1, wc = wave & 1;
  f32x4 acc[4][4] = {};
  int srow = tid >> 3;
  int scol = (tid & 7) * 8;
  const ushort* Abase = A + (size_t)(m0 + srow)*K + scol;
  const ushort* Bbase = Bt + (size_t)(n0 + srow)*K + scol;
  for (int k0 = 0; k0 < K; k0 += 64) {
    #pragma unroll
    for (int c = 0; c < 4; ++c)
      __builtin_amdgcn_global_load_lds((gptr_t)(Abase + (size_t)c*32*K + k0),
                                       (lptr_t)&Ash[(srow + c*32)*64 + scol], 16, 0, 0);
    #pragma unroll
    for (int c = 0; c < 4; ++c)
      __builtin_amdgcn_global_load_lds((gptr_t)(Bbase + (size_t)c*32*K + k0),
                                       (lptr_t)&Bsh[(srow + c*32)*64 + scol], 16, 0, 0);
    __syncthreads();
    #pragma unroll
    for (int kk = 0; kk < 2; ++kk) {
      short8 a[4], b[4];
      #pragma unroll
      for (int m=0;m<4;m++) a[m] = *(const short8*)&Ash[(wr*64 + m*16 + lo)*64 + kk*32 + hi*8];
      #pragma unroll
      for (int n=0;n<4;n++) b[n] = *(const short8*)&Bsh[(wc*64 + n*16 + lo)*64 + kk*32 + hi*8];
      #pragma unroll
      for (int m=0;m<4;m++)
        #pragma unroll
        for (int n=0;n<4;n++)
          acc[m][n] = __builtin_amdgcn_mfma_f32_16x16x32_bf16(a[m], b[n], acc[m][n], 0, 0, 0);
    }
    __syncthreads();
  }
  const float QSCALE = 0.08838834764831845f * 1.4426950408889634f; // 1/sqrt(HD)*log2(e)
  #pragma unroll
  for (int m=0;m<4;m++) {
    int row0 = m0 + wr*64 + m*16 + hi*4;          // global token, multiple of 4
    int bb = row0 >> 11, t0 = row0 & 2047;
    #pragma unroll
    for (int n=0;n<4;n++) {
      int col = n0 + wc*64 + n*16 + lo;           // feature 0..3071; parity(col)==parity(lo)
      f32x4 a = acc[m][n];
      if (col < 2048) {                           // Q: rope + scale -> q_bf
        int hh = col >> 7, d = col & 127, jj = d >> 1;
        bool ev = (d & 1) == 0;
        #pragma unroll
        for (int r=0;r<4;r++) {
          float p = __shfl_xor(a[r], 1);
          float2 cs = ((const float2*)freqs)[(size_t)(t0 + r)*64 + jj];
          float o = ev ? (a[r]*cs.x - p*cs.y) : (a[r]*cs.x + p*cs.y);
          q_bf[((size_t)(bb*NH + hh)*T_ + t0 + r)*HD + d] = f2bf(o * QSCALE);
        }
      } else if (col < 2560) {                    // K: rope -> k_bf + kcache
        int cg = col - 2048;
        int gg = cg >> 7, d = cg & 127, jj = d >> 1;
        bool ev = (d & 1) == 0;
        #pragma unroll
        for (int r=0;r<4;r++) {
          float p = __shfl_xor(a[r], 1);
          float2 cs = ((const float2*)freqs)[(size_t)(t0 + r)*64 + jj];
          float o = ev ? (a[r]*cs.x - p*cs.y) : (a[r]*cs.x + p*cs.y);
          size_t idx = ((size_t)(bb*NKV + gg)*T_ + t0 + r)*HD + d;
          k_bf[idx] = f2bf(o);
          kcache[idx] = o;
        }
      } else {                                    // V: vcache f32 + v_t transposed bf16
        int cg = col - 2560;
        int gg = cg >> 7, d = cg & 127;
        short4_t pk;
        #pragma unroll
        for (int r=0;r<4;r++) {
          vcache[((size_t)(bb*NKV + gg)*T_ + t0 + r)*HD + d] = a[r];
          pk[r] = (short)f2bf(a[r]);
        }
        *(short4_t*)&v_t[((size_t)(bb*NKV + gg)*HD + d)*T_ + t0] = pk;
      }
    }
  }
}

// ---------- flash attention: 64 q-rows/block, KVBLK=64, swapped QK^T ----------
// K double-buffered in LDS with T14 split staging (loads early, ds_write after PV),
// ONE barrier per iteration. Raw v_exp_f32 softmax, cvt_pk P-pack, defer-max (THR=8).
// grid: 1024 blocks; qt remapped so each CU's block set {id, id+256, id+512, id+768}
// has qts {u, 15-u, 16+u, 31-u} -> constant 66 kv64-tile-iters per CU.
__global__ __launch_bounds__(256) void attn_kernel(const ushort* __restrict__ Qb, const ushort* __restrict__ Kb,
                          const ushort* __restrict__ Vt, ushort* __restrict__ O) {
  __shared__ ushort Ksh[2][64][144];   // 288B row: <=4-way bank pattern on b128 reads
  __shared__ unsigned Pshu[4][16][40]; // per-wave P (16q x 64kv), dword-packed
  int id = blockIdx.x;
  int j = id >> 5, hb = id & 31;
  int t2 = j >> 3, u = j & 7;
  int qt = (t2==0) ? u : (t2==1) ? 15-u : (t2==2) ? 16+u : 31-u;
  int h = hb & 15, b = hb >> 4, g = h >> 2;
  int tid = threadIdx.x, wave = tid >> 6, lane = tid & 63;
  int lo = lane & 15, hi = lane >> 4;
  int q0 = qt*64 + wave*16;
  const ushort* Qrow = Qb + ((size_t)(b*NH + h)*T_ + q0 + lo)*HD;
  short8 qfr[4];
  #pragma unroll
  for (int kf=0;kf<4;kf++) qfr[kf] = *(const short8*)(Qrow + kf*32 + hi*8);
  f32x4 o[8] = {};
  float m_run = -1e30f, l_run = 0.f;   // this lane's q-row = q0 + lo
  const ushort* Kbase = Kb + (size_t)(b*NKV + g)*T_*HD;
  const ushort* Vbase = Vt + (size_t)(b*NKV + g)*HD*T_;
  int ntiles = qt + 1;
  int sr = tid >> 4, scl8 = (tid & 15)*8;   // staging: 16 lanes x 8 ush per row
  // prologue: stage K tile 0 into buf 0
  #pragma unroll
  for (int c=0;c<4;c++)
    *(short8*)&Ksh[0][sr + c*16][scl8] = *(const short8*)(Kbase + (size_t)(sr + c*16)*HD + scl8);
  __syncthreads();
  int cur = 0;
  for (int it = 0; it < ntiles; ++it) {
    int kv0 = it*64;
    // T14: issue next K-tile global loads now; LDS-write after PV
    short8 kreg[4];
    bool pre = (it+1 < ntiles);
    if (pre) {
      #pragma unroll
      for (int c=0;c<4;c++)
        kreg[c] = *(const short8*)(Kbase + (size_t)(kv0 + 64 + sr + c*16)*HD + scl8);
    }
    // S^T = K * Q^T : s[nf][r] = S[q0+lo][kv0 + nf*16 + hi*4 + r]
    f32x4 s[4];
    __builtin_amdgcn_s_setprio(1);
    #pragma unroll
    for (int nf=0;nf<4;nf++) {
      s[nf] = (f32x4){0.f,0.f,0.f,0.f};
      #pragma unroll
      for (int kf=0;kf<4;kf++) {
        short8 bk = *(const short8*)&Ksh[cur][nf*16 + lo][kf*32 + hi*8];
        s[nf] = __builtin_amdgcn_mfma_f32_16x16x32_bf16(bk, qfr[kf], s[nf], 0,0,0);
      }
    }
    __builtin_amdgcn_s_setprio(0);
    if (it == ntiles-1) {
      int qg = q0 + lo;
      #pragma unroll
      for (int nf=0;nf<4;nf++)
        #pragma unroll
        for (int r=0;r<4;r++) {
          int kvg = kv0 + nf*16 + hi*4 + r;
          if (kvg > qg) s[nf][r] = -1e30f;
        }
    }
    // in-lane softmax over this lane's 16 S-values; reduce across hi groups (2 levels)
    float mx = -1e30f;
    #pragma unroll
    for (int nf=0;nf<4;nf++)
      #pragma unroll
      for (int r=0;r<4;r++) mx = fmaxf(mx, s[nf][r]);
    mx = fmaxf(mx, __shfl_xor(mx, 16));
    mx = fmaxf(mx, __shfl_xor(mx, 32));
    // T13 defer-max: skip rescale when per-tile max growth <= 8 (P bounded by 2^8)
    if (!__all(mx - m_run <= 8.0f)) {
      float nm = fmaxf(m_run, mx);
      float scl = fast_exp2(m_run - nm);
      float ps[4];
      #pragma unroll
      for (int r=0;r<4;r++) ps[r] = __shfl(scl, (lane & 48) + hi*4 + r);
      #pragma unroll
      for (int df=0;df<8;df++)
        #pragma unroll
        for (int r=0;r<4;r++) o[df][r] *= ps[r];
      l_run *= scl;
      m_run = nm;
    }
    float rs = 0.f;
    #pragma unroll
    for (int nf=0;nf<4;nf++)
      #pragma unroll
      for (int r=0;r<4;r++) { float pv = fast_exp2(s[nf][r] - m_run); s[nf][r] = pv; rs += pv; }
    rs += __shfl_xor(rs, 16);
    rs += __shfl_xor(rs, 32);
    l_run += rs;
    // P -> LDS (cvt_pk packed): row q=lo, ushort cols kv = nf*16 + hi*4 + {0..3}
    #pragma unroll
    for (int nf=0;nf<4;nf++) {
      Pshu[wave][lo][nf*8 + hi*2]     = cvt_pk_bf16(s[nf][0], s[nf][1]);
      Pshu[wave][lo][nf*8 + hi*2 + 1] = cvt_pk_bf16(s[nf][2], s[nf][3]);
    }
    asm volatile("s_waitcnt lgkmcnt(0)" ::: "memory");
    short8 pa[2];
    #pragma unroll
    for (int k2=0;k2<2;k2++)
      pa[k2] = *(const short8*)&((const ushort*)&Pshu[wave][lo][0])[k2*32 + hi*8];
    __builtin_amdgcn_s_setprio(1);
    #pragma unroll
    for (int df=0;df<8;df++) {
      #pragma unroll
      for (int k2=0;k2<2;k2++) {
        short8 bv = *(const short8*)(Vbase + (size_t)(df*16 + lo)*T_ + kv0 + k2*32 + hi*8);
        o[df] = __builtin_amdgcn_mfma_f32_16x16x32_bf16(pa[k2], bv, o[df], 0,0,0);
      }
    }
    __builtin_amdgcn_s_setprio(0);
    // write prefetched K into the other buffer (readers of it wait at the barrier)
    if (pre) {
      #pragma unroll
      for (int c=0;c<4;c++)
        *(short8*)&Ksh[cur^1][sr + c*16][scl8] = kreg[c];
    }
    __syncthreads();
    cur ^= 1;
  }
  #pragma unroll
  for (int r=0;r<4;r++) {
    float li = __shfl(l_run, (lane & 48) + hi*4 + r);
    float inv = 1.0f / li;
    int qg = q0 + hi*4 + r;
    size_t base = ((size_t)(b*T_) + qg)*DIM + (size_t)h*HD;
    #pragma unroll
    for (int df=0;df<8;df++)
      O[base + df*16 + lo] = f2bf(o[df][r] * inv);
  }
}

extern "C" void kernel_launch(void* const* d_in, const int* in_sizes, int n_in,
                              void* d_out, int out_size, void* d_ws, size_t ws_size,
                              hipStream_t stream) {
  const float* x     = (const float*)d_in[0];
  const float* wq    = (const float*)d_in[1];
  const float* wk    = (const float*)d_in[2];
  const float* wv    = (const float*)d_in[3];
  const float* wo    = (const float*)d_in[4];
  const float* freqs = (const float*)d_in[5];
  float* out    = (float*)d_out;
  float* kcache = out + (size_t)B_*T_*DIM;
  float* vcache = kcache + (size_t)B_*NKV*T_*HD;

  char* ws = (char*)d_ws;
  size_t off = 0;
  auto alloc = [&](size_t bytes) { char* p = ws + off; off += (bytes + 255) & ~255ULL; return p; };
  ushort* x_bf   = (ushort*)alloc((size_t)M_TOT*DIM*2);
  ushort* wqkv_t = (ushort*)alloc((size_t)NQKV*DIM*2);  // rows: 2048 q, 512 k, 512 v (each [n][K])
  ushort* wo_t   = (ushort*)alloc((size_t)DIM*DIM*2);
  ushort* q_bf   = (ushort*)alloc((size_t)B_*NH*T_*HD*2);
  ushort* k_bf   = (ushort*)alloc((size_t)B_*NKV*T_*HD*2);
  ushort* v_t    = (ushort*)alloc((size_t)B_*NKV*HD*T_*2);
  ushort* ao_bf  = (ushort*)alloc((size_t)M_TOT*DIM*2);
  (void)ws_size; (void)in_sizes; (void)n_in; (void)out_size;

  prep_kernel<<<14336, 256, 0, stream>>>(x, wq, wk, wv, wo, x_bf, wqkv_t, wo_t);

  gemm_qkv_rope<<<dim3(NQKV/128, M_TOT/128), 256, 0, stream>>>(
      x_bf, wqkv_t, freqs, q_bf, k_bf, kcache, vcache, v_t);

  attn_kernel<<<1024, 256, 0, stream>>>(q_bf, k_bf, v_t, ao_bf);

  gemm_bt<<<dim3(DIM/128, M_TOT/128), 256, 0, stream>>>(ao_bf, wo_t, out, M_TOT, DIM, DIM);
}